// Round 7
// baseline (86.663 us; speedup 1.0000x reference)
//
#include <hip/hip_runtime.h>
#include <math.h>

#define BB 32
#define NN 2048
#define TB 128            // k1 threads
#define QT 16             // queries per thread in k1 -> 2048 = NN per block
#define RCH 32            // ref chunks (split of the min over refs)
#define MCH (NN / RCH)    // 64 refs per chunk
#define TB2 512           // k2 threads

typedef float v2f __attribute__((ext_vector_type(2)));

// ws layout: part[RCH][2*BB][NN] floats (16.8 MB, no init needed)

__device__ __forceinline__ float wred(float v) {
#pragma unroll
    for (int o = 32; o > 0; o >>= 1) v += __shfl_down(v, o, 64);
    return v;
}

// K1: grid (1, BB, 2*RCH); blockIdx.z = rc*2 + role. 2048 blocks = 8/CU =
// 16 waves/CU (4/SIMD). QT=16 halves LDS reads per query vs QT=8/TB=256.
// Inner loop in float2 -> v_pk_fma_f32: 4 pk_fma + 2 v_min3 per 4 refs per
// query = 1.5 VALU/pair. Block (0,0) zeroes out[]; the k1->k2 dispatch
// boundary is the cross-XCD release fence (R5: device __threadfence storms
// cost ~100us — never again at this grain).
__global__ __launch_bounds__(128) void k1_chamfer(
    const float* __restrict__ pred, const float* __restrict__ tgt,
    float* __restrict__ part, float* __restrict__ out)
{
    __shared__ float sa[MCH], sb[MCH], sc[MCH];

    const int tid  = threadIdx.x;
    const int b    = blockIdx.y;
    const int role = blockIdx.z & 1;
    const int rc   = blockIdx.z >> 1;

    if (b == 0 && blockIdx.z == 0 && tid < 4) out[tid] = 0.0f;

    const float* q = role ? tgt : pred;
    const float* r = role ? pred : tgt;
    const float* rb = r + ((size_t)b * NN + (size_t)rc * MCH) * 3;

    // Stage refs in norm form; invisible refs poisoned far (d2 ~ 2e18).
    if (tid < MCH) {
        float rx = rb[3 * tid + 0];
        float ry = rb[3 * tid + 1];
        float rv = rb[3 * tid + 2];
        if (rv != 1.0f) { rx = 1.0e9f; ry = 1.0e9f; }
        sa[tid] = -2.0f * rx;
        sb[tid] = -2.0f * ry;
        sc[tid] = fmaf(rx, rx, ry * ry);
    }
    __syncthreads();

    const float* qb_ = q + (size_t)b * NN * 3;
    float px[QT], py[QT], mn[QT];
#pragma unroll
    for (int j = 0; j < QT; j++) {
        int qi = tid + j * TB;
        px[j] = qb_[3 * qi + 0];
        py[j] = qb_[3 * qi + 1];
        mn[j] = 3.4e38f;
    }

    // 4 refs/iter: 3 uniform ds_read_b128 (broadcast, conflict-free), then
    // per query 4 v_pk_fma_f32 + 2 v_min3_f32.
#pragma unroll 2
    for (int m = 0; m < MCH; m += 4) {
        float4 a4 = *(const float4*)&sa[m];
        float4 b4 = *(const float4*)&sb[m];
        float4 c4 = *(const float4*)&sc[m];
        v2f a01 = {a4.x, a4.y}, a23 = {a4.z, a4.w};
        v2f b01 = {b4.x, b4.y}, b23 = {b4.z, b4.w};
        v2f c01 = {c4.x, c4.y}, c23 = {c4.z, c4.w};
#pragma unroll
        for (int j = 0; j < QT; j++) {
            v2f pxs = {px[j], px[j]};
            v2f pys = {py[j], py[j]};
            v2f t01 = __builtin_elementwise_fma(pys, b01, c01);
            v2f t23 = __builtin_elementwise_fma(pys, b23, c23);
            v2f s01 = __builtin_elementwise_fma(pxs, a01, t01);
            v2f s23 = __builtin_elementwise_fma(pxs, a23, t23);
            // two v_min3_f32
            mn[j] = fminf(fminf(s01.x, s01.y),
                          fminf(fminf(s23.x, s23.y), mn[j]));
        }
    }

#pragma unroll
    for (int j = 0; j < QT; j++) {
        int qi = tid + j * TB;
        float qn = fmaf(px[j], px[j], py[j] * py[j]);
        part[((size_t)rc * (2 * BB) + role * BB + b) * NN + qi] = qn + mn[j];
    }
}

// K2: grid (BB) = 32 blocks, 512 threads. Block b owns batch b, BOTH roles:
// combine 32 planes per query, sqrt+mask epilogue, block-reduce 7 sums,
// compute chamfer_b locally, atomicAdd the (linear) output terms.
// smk>0 gate is redundant: smk==0 => every struct term is 0 => sum is 0.
__global__ __launch_bounds__(TB2) void k2_final(
    const float* __restrict__ pred, const float* __restrict__ tgt,
    const float* __restrict__ smask, const float* __restrict__ part,
    float* __restrict__ out)
{
    __shared__ float sred[7][8];
    const int tid = threadIdx.x;
    const int b   = blockIdx.x;

    float a0 = 0, a1 = 0, a2 = 0, a3 = 0, a4 = 0, a5 = 0, a6 = 0;

    // role 0 (queries = pred): contrib_p, cnt_p, point/struct/mask sums
#pragma unroll
    for (int j = 0; j < NN / TB2; j++) {
        int qi = tid + j * TB2;
        float m = 3.4e38f;
#pragma unroll
        for (int k = 0; k < RCH; k++)
            m = fminf(m, part[((size_t)k * (2 * BB) + b) * NN + qi]);

        const float* qp = pred + ((size_t)b * NN + qi) * 3;
        float qvf = (qp[2] == 1.0f) ? 1.0f : 0.0f;
        a0 += sqrtf(fmaxf(m, 1e-12f)) * qvf;
        a1 += qvf;

        const float* tp = tgt + ((size_t)b * NN + qi) * 3;
        float vm = (tp[2] == 1.0f) ? 1.0f : 0.0f;
        float dx = qp[0] - tp[0], dy = qp[1] - tp[1];
        float e2 = fmaf(dx, dx, dy * dy);
        float s0 = smask[((size_t)b * NN + qi) * 2 + 0];
        float s1 = smask[((size_t)b * NN + qi) * 2 + 1];
        float tm = fminf(fmaxf(s0 + s1, 0.0f), 1.0f) * vm;
        a2 += e2 * vm;
        a3 += e2 * tm;
        a4 += tm;
    }

    // role 1 (queries = tgt): contrib_t, cnt_t
#pragma unroll
    for (int j = 0; j < NN / TB2; j++) {
        int qi = tid + j * TB2;
        float m = 3.4e38f;
#pragma unroll
        for (int k = 0; k < RCH; k++)
            m = fminf(m, part[((size_t)k * (2 * BB) + BB + b) * NN + qi]);

        const float* qp = tgt + ((size_t)b * NN + qi) * 3;
        float qvf = (qp[2] == 1.0f) ? 1.0f : 0.0f;
        a5 += sqrtf(fmaxf(m, 1e-12f)) * qvf;
        a6 += qvf;
    }

    float v[7] = {a0, a1, a2, a3, a4, a5, a6};
    const int wave = tid >> 6, lane = tid & 63;
#pragma unroll
    for (int i = 0; i < 7; i++) {
        float rv = wred(v[i]);
        if (lane == 0) sred[i][wave] = rv;
    }
    __syncthreads();

    if (tid == 0) {
        float s[7];
#pragma unroll
        for (int i = 0; i < 7; i++) {
            float acc = 0.0f;
#pragma unroll
            for (int w = 0; w < TB2 / 64; w++) acc += sred[i][w];
            s[i] = acc;
        }
        float sp = s[0], cp = s[1], spt = s[2], sst = s[3];
        float st_ = s[5], ct = s[6];
        float mp = sp / fmaxf(cp, 1.0f);
        float mt = st_ / fmaxf(ct, 1.0f);
        float ch = (cp > 0.0f && ct > 0.0f) ? 0.5f * (mp + mt) : 0.0f;

        const float denom = (float)BB * (float)NN * 2.0f;
        float lp = spt / denom;          // loss_point contribution (batch b)
        float ls = sst / denom;          // loss_struct contribution
        float lc = ch / (float)BB;       // loss_chamfer contribution

        atomicAdd(&out[0], lp + 5.0f * lc + 2.0f * ls);
        atomicAdd(&out[1], lp);
        atomicAdd(&out[3], lc);
        // out[2] stays 0 (zeroed by k1)
    }
}

extern "C" void kernel_launch(void* const* d_in, const int* in_sizes, int n_in,
                              void* d_out, int out_size, void* d_ws, size_t ws_size,
                              hipStream_t stream)
{
    const float* pred  = (const float*)d_in[0];
    const float* tgt   = (const float*)d_in[1];
    const float* smask = (const float*)d_in[2];
    float* out = (float*)d_out;
    float* part = (float*)d_ws;   // 16.8 MB

    k1_chamfer<<<dim3(1, BB, 2 * RCH), TB, 0, stream>>>(pred, tgt, part, out);
    k2_final<<<dim3(BB), TB2, 0, stream>>>(pred, tgt, smask, part, out);
}

// Round 8
// 81.909 us; speedup vs baseline: 1.0580x; 1.0580x over previous
//
#include <hip/hip_runtime.h>
#include <math.h>

#define BB 32
#define NN 2048
#define TB 256            // k1 threads
#define QT 8              // queries per thread in k1 -> 2048 = NN per block
#define RCH 16            // ref chunks (split of the min over refs)
#define MCH (NN / RCH)    // 128 refs per chunk
#define TB2 1024          // k2 threads

// ws layout: part[RCH][2*BB][NN] floats (8.4 MB, no init needed)

__device__ __forceinline__ float wred(float v) {
#pragma unroll
    for (int o = 32; o > 0; o >>= 1) v += __shfl_down(v, o, 64);
    return v;
}

// K1 — identical to the round-6 best (80.3us). grid (1, BB, 2*RCH);
// blockIdx.z = rc*2 + role; 1024 blocks = 4/CU = 16 waves/CU.
// 8 refs/iter: 6 uniform ds_read_b128 (broadcast), per query 16 fma +
// 4 v_min3 -> 2.5 VALU/pair. Block (0,0) zeroes out[]; the k1->k2 dispatch
// boundary is the cross-XCD release fence (R5: __threadfence storms = ~100us).
__global__ __launch_bounds__(256) void k1_chamfer(
    const float* __restrict__ pred, const float* __restrict__ tgt,
    float* __restrict__ part, float* __restrict__ out)
{
    __shared__ float sa[MCH], sb[MCH], sc[MCH];

    const int tid  = threadIdx.x;
    const int b    = blockIdx.y;
    const int role = blockIdx.z & 1;
    const int rc   = blockIdx.z >> 1;

    if (b == 0 && blockIdx.z == 0 && tid < 4) out[tid] = 0.0f;

    const float* q = role ? tgt : pred;
    const float* r = role ? pred : tgt;
    const float* rb = r + ((size_t)b * NN + (size_t)rc * MCH) * 3;

    if (tid < MCH) {
        float rx = rb[3 * tid + 0];
        float ry = rb[3 * tid + 1];
        float rv = rb[3 * tid + 2];
        if (rv != 1.0f) { rx = 1.0e9f; ry = 1.0e9f; }   // d2 ~ 2e18, never wins
        sa[tid] = -2.0f * rx;
        sb[tid] = -2.0f * ry;
        sc[tid] = fmaf(rx, rx, ry * ry);
    }
    __syncthreads();

    const float* qb_ = q + (size_t)b * NN * 3;
    float px[QT], py[QT], mn[QT];
#pragma unroll
    for (int j = 0; j < QT; j++) {
        int qi = tid + j * TB;
        px[j] = qb_[3 * qi + 0];
        py[j] = qb_[3 * qi + 1];
        mn[j] = 3.4e38f;
    }

#pragma unroll 2
    for (int m = 0; m < MCH; m += 8) {
        float4 a0 = *(const float4*)&sa[m], a1 = *(const float4*)&sa[m + 4];
        float4 b0 = *(const float4*)&sb[m], b1 = *(const float4*)&sb[m + 4];
        float4 c0 = *(const float4*)&sc[m], c1 = *(const float4*)&sc[m + 4];
#pragma unroll
        for (int j = 0; j < QT; j++) {
            float s0 = fmaf(px[j], a0.x, fmaf(py[j], b0.x, c0.x));
            float s1 = fmaf(px[j], a0.y, fmaf(py[j], b0.y, c0.y));
            float s2 = fmaf(px[j], a0.z, fmaf(py[j], b0.z, c0.z));
            float s3 = fmaf(px[j], a0.w, fmaf(py[j], b0.w, c0.w));
            float s4 = fmaf(px[j], a1.x, fmaf(py[j], b1.x, c1.x));
            float s5 = fmaf(px[j], a1.y, fmaf(py[j], b1.y, c1.y));
            float s6 = fmaf(px[j], a1.z, fmaf(py[j], b1.z, c1.z));
            float s7 = fmaf(px[j], a1.w, fmaf(py[j], b1.w, c1.w));
            float u = fminf(fminf(s0, s1), s2);
            float v = fminf(fminf(s3, s4), s5);
            float w = fminf(fminf(s6, s7), mn[j]);
            mn[j] = fminf(fminf(u, v), w);
        }
    }

#pragma unroll
    for (int j = 0; j < QT; j++) {
        int qi = tid + j * TB;
        float qn = fmaf(px[j], px[j], py[j] * py[j]);
        part[((size_t)rc * (2 * BB) + role * BB + b) * NN + qi] = qn + mn[j];
    }
}

// K2 — rebuilt for parallelism: grid (2, BB, 2) = 128 blocks x 1024 thr
// (vs 32 blocks before: 12.5% CU use, latency-chained loads). One query per
// thread, one 16-plane min. Each block recomputes the FULL batch visibility
// counts itself (strided reads of both v-columns, L2/L3-hit), so its output
// contribution is linear and finishes with <=4 atomicAdds into out[].
__global__ __launch_bounds__(TB2) void k2_final(
    const float* __restrict__ pred, const float* __restrict__ tgt,
    const float* __restrict__ smask, const float* __restrict__ part,
    float* __restrict__ out)
{
    __shared__ float sred[6][16];
    const int tid  = threadIdx.x;
    const int b    = blockIdx.y;
    const int role = blockIdx.z;
    const int qi   = blockIdx.x * TB2 + tid;

    // 16-plane min for this thread's query
    float m = 3.4e38f;
#pragma unroll
    for (int k = 0; k < RCH; k++)
        m = fminf(m, part[((size_t)k * (2 * BB) + role * BB + b) * NN + qi]);

    const float* qp = (role ? tgt : pred) + ((size_t)b * NN + qi) * 3;
    float qvf = (qp[2] == 1.0f) ? 1.0f : 0.0f;
    float contrib = sqrtf(fmaxf(m, 1e-12f)) * qvf;

    // Full-batch visibility counts (both roles), recomputed per block.
    float cnt_p = 0.0f, cnt_t = 0.0f;
#pragma unroll
    for (int j = 0; j < NN / TB2; j++) {
        int i = tid + j * TB2;
        cnt_p += (pred[((size_t)b * NN + i) * 3 + 2] == 1.0f) ? 1.0f : 0.0f;
        cnt_t += (tgt[((size_t)b * NN + i) * 3 + 2] == 1.0f) ? 1.0f : 0.0f;
    }

    // Point/structure partial sums (role-0 blocks only; each query once).
    float pt = 0.0f, st = 0.0f;
    if (role == 0) {
        const float* tp = tgt + ((size_t)b * NN + qi) * 3;
        float vm = (tp[2] == 1.0f) ? 1.0f : 0.0f;
        float dx = qp[0] - tp[0], dy = qp[1] - tp[1];
        float e2 = fmaf(dx, dx, dy * dy);
        float s0 = smask[((size_t)b * NN + qi) * 2 + 0];
        float s1 = smask[((size_t)b * NN + qi) * 2 + 1];
        float tm = fminf(fmaxf(s0 + s1, 0.0f), 1.0f) * vm;
        pt = e2 * vm;
        st = e2 * tm;
        // smk>0 gate is redundant: smk==0 => every struct term is 0.
    }

    float v[6] = {contrib, cnt_p, cnt_t, pt, st, 0.0f};
    const int wave = tid >> 6, lane = tid & 63;
#pragma unroll
    for (int i = 0; i < 5; i++) {
        float rv = wred(v[i]);
        if (lane == 0) sred[i][wave] = rv;
    }
    __syncthreads();

    if (tid == 0) {
        float s[5];
#pragma unroll
        for (int i = 0; i < 5; i++) {
            float acc = 0.0f;
#pragma unroll
            for (int w = 0; w < TB2 / 64; w++) acc += sred[i][w];
            s[i] = acc;
        }
        float cp = s[1], ct = s[2];
        // counts are full-batch; contrib sum is this block's partial -> the
        // per-block chamfer contribution is linear given the counts.
        float cnt_mine = role ? ct : cp;
        float gate = (cp > 0.0f && ct > 0.0f) ? 1.0f : 0.0f;
        float lc = gate * 0.5f * (s[0] / fmaxf(cnt_mine, 1.0f)) / (float)BB;

        const float denom = (float)BB * (float)NN * 2.0f;
        if (role == 0) {
            float lp = s[3] / denom;
            float ls = s[4] / denom;
            atomicAdd(&out[0], lp + 5.0f * lc + 2.0f * ls);
            atomicAdd(&out[1], lp);
        } else {
            atomicAdd(&out[0], 5.0f * lc);
        }
        atomicAdd(&out[3], lc);
        // out[2] stays 0 (zeroed by k1)
    }
}

extern "C" void kernel_launch(void* const* d_in, const int* in_sizes, int n_in,
                              void* d_out, int out_size, void* d_ws, size_t ws_size,
                              hipStream_t stream)
{
    const float* pred  = (const float*)d_in[0];
    const float* tgt   = (const float*)d_in[1];
    const float* smask = (const float*)d_in[2];
    float* out = (float*)d_out;
    float* part = (float*)d_ws;   // 8.4 MB

    k1_chamfer<<<dim3(1, BB, 2 * RCH), TB, 0, stream>>>(pred, tgt, part, out);
    k2_final<<<dim3(2, BB, 2), TB2, 0, stream>>>(pred, tgt, smask, part, out);
}

// Round 9
// 81.346 us; speedup vs baseline: 1.0654x; 1.0069x over previous
//
#include <hip/hip_runtime.h>
#include <math.h>

#define BB 32
#define NN 2048
#define TB 256            // k1 threads: two 128-thread role-halves
#define HT 128            // threads per role-half
#define HQT 16            // queries per thread (per role-half) -> 16*128 = 2048
#define RCH 16            // ref chunks
#define MCH (NN / RCH)    // 128 refs per chunk (== HT)
#define TB2 512           // k2 threads

// ws layout: part[RCH][2*BB][NN] floats (8.4 MB, no init needed)

__device__ __forceinline__ float wred(float v) {
#pragma unroll
    for (int o = 32; o > 0; o >>= 1) v += __shfl_down(v, o, 64);
    return v;
}

// K1: grid (1, BB, RCH) = 512 blocks (2/CU, 8 waves/CU). Block handles BOTH
// roles of (b, rc): waves 0-1 = role 0 (queries=pred, refs=tgt), waves 2-3 =
// role 1. QT=16/role -> one 6-ds_read group serves 8 refs x 16 queries
// (21.3 pairs/read, 2x the previous 10.7) — halves per-CU LDS-pipe cycles
// while VALU work is unchanged. Role is wave-uniform so LDS reads stay
// broadcast/conflict-free. Block (0,0) zeroes out[]; k1->k2 dispatch boundary
// is the cross-XCD release fence (R5: __threadfence storms = ~100us).
__global__ __launch_bounds__(256) void k1_chamfer(
    const float* __restrict__ pred, const float* __restrict__ tgt,
    float* __restrict__ part, float* __restrict__ out)
{
    __shared__ float sa[2][MCH], sb[2][MCH], sc[2][MCH];

    const int tid  = threadIdx.x;
    const int b    = blockIdx.y;
    const int rc   = blockIdx.z;
    const int role = tid >> 7;    // wave-aligned role halves
    const int lt   = tid & (HT - 1);

    if (b == 0 && rc == 0 && tid < 4) out[tid] = 0.0f;

    // Stage this half's ref chunk (MCH == HT: one ref per thread).
    {
        const float* r = role ? pred : tgt;
        const float* rb = r + ((size_t)b * NN + (size_t)rc * MCH) * 3;
        float rx = rb[3 * lt + 0];
        float ry = rb[3 * lt + 1];
        float rv = rb[3 * lt + 2];
        if (rv != 1.0f) { rx = 1.0e9f; ry = 1.0e9f; }   // d2 ~ 2e18, never wins
        sa[role][lt] = -2.0f * rx;
        sb[role][lt] = -2.0f * ry;
        sc[role][lt] = fmaf(rx, rx, ry * ry);
    }
    __syncthreads();

    const float* qb_ = (role ? tgt : pred) + (size_t)b * NN * 3;
    float px[HQT], py[HQT], mn[HQT];
#pragma unroll
    for (int j = 0; j < HQT; j++) {
        int qi = lt + j * HT;
        px[j] = qb_[3 * qi + 0];
        py[j] = qb_[3 * qi + 1];
        mn[j] = 3.4e38f;
    }

    const float* A = sa[role];
    const float* Bv = sb[role];
    const float* Cv = sc[role];

    // 8 refs/iter: 6 uniform ds_read_b128, then per query 16 fma + 4 v_min3
    // -> 2.5 VALU/pair at 21.3 pairs per ds_read.
#pragma unroll 2
    for (int m = 0; m < MCH; m += 8) {
        float4 a0 = *(const float4*)&A[m],  a1 = *(const float4*)&A[m + 4];
        float4 b0 = *(const float4*)&Bv[m], b1 = *(const float4*)&Bv[m + 4];
        float4 c0 = *(const float4*)&Cv[m], c1 = *(const float4*)&Cv[m + 4];
#pragma unroll
        for (int j = 0; j < HQT; j++) {
            float s0 = fmaf(px[j], a0.x, fmaf(py[j], b0.x, c0.x));
            float s1 = fmaf(px[j], a0.y, fmaf(py[j], b0.y, c0.y));
            float s2 = fmaf(px[j], a0.z, fmaf(py[j], b0.z, c0.z));
            float s3 = fmaf(px[j], a0.w, fmaf(py[j], b0.w, c0.w));
            float s4 = fmaf(px[j], a1.x, fmaf(py[j], b1.x, c1.x));
            float s5 = fmaf(px[j], a1.y, fmaf(py[j], b1.y, c1.y));
            float s6 = fmaf(px[j], a1.z, fmaf(py[j], b1.z, c1.z));
            float s7 = fmaf(px[j], a1.w, fmaf(py[j], b1.w, c1.w));
            float u = fminf(fminf(s0, s1), s2);
            float v = fminf(fminf(s3, s4), s5);
            float w = fminf(fminf(s6, s7), mn[j]);
            mn[j] = fminf(fminf(u, v), w);
        }
    }

#pragma unroll
    for (int j = 0; j < HQT; j++) {
        int qi = lt + j * HT;
        float qn = fmaf(px[j], px[j], py[j] * py[j]);
        part[((size_t)rc * (2 * BB) + role * BB + b) * NN + qi] = qn + mn[j];
    }
}

// K2 — exact round-6 version (proven best): grid (BB) = 32 blocks, 512 thr.
// Block b owns batch b, BOTH roles: 16-plane min per query, sqrt+mask
// epilogue, block-reduce 7 sums, chamfer_b local, atomicAdd linear terms.
// smk>0 gate is redundant: smk==0 => every struct term is 0 => sum is 0.
__global__ __launch_bounds__(TB2) void k2_final(
    const float* __restrict__ pred, const float* __restrict__ tgt,
    const float* __restrict__ smask, const float* __restrict__ part,
    float* __restrict__ out)
{
    __shared__ float sred[7][8];
    const int tid = threadIdx.x;
    const int b   = blockIdx.x;

    float a0 = 0, a1 = 0, a2 = 0, a3 = 0, a4 = 0, a5 = 0, a6 = 0;

    // role 0 (queries = pred): contrib_p, cnt_p, point/struct/mask sums
#pragma unroll
    for (int j = 0; j < NN / TB2; j++) {
        int qi = tid + j * TB2;
        float m = 3.4e38f;
#pragma unroll
        for (int k = 0; k < RCH; k++)
            m = fminf(m, part[((size_t)k * (2 * BB) + b) * NN + qi]);

        const float* qp = pred + ((size_t)b * NN + qi) * 3;
        float qvf = (qp[2] == 1.0f) ? 1.0f : 0.0f;
        a0 += sqrtf(fmaxf(m, 1e-12f)) * qvf;
        a1 += qvf;

        const float* tp = tgt + ((size_t)b * NN + qi) * 3;
        float vm = (tp[2] == 1.0f) ? 1.0f : 0.0f;
        float dx = qp[0] - tp[0], dy = qp[1] - tp[1];
        float e2 = fmaf(dx, dx, dy * dy);
        float s0 = smask[((size_t)b * NN + qi) * 2 + 0];
        float s1 = smask[((size_t)b * NN + qi) * 2 + 1];
        float tm = fminf(fmaxf(s0 + s1, 0.0f), 1.0f) * vm;
        a2 += e2 * vm;
        a3 += e2 * tm;
        a4 += tm;
    }

    // role 1 (queries = tgt): contrib_t, cnt_t
#pragma unroll
    for (int j = 0; j < NN / TB2; j++) {
        int qi = tid + j * TB2;
        float m = 3.4e38f;
#pragma unroll
        for (int k = 0; k < RCH; k++)
            m = fminf(m, part[((size_t)k * (2 * BB) + BB + b) * NN + qi]);

        const float* qp = tgt + ((size_t)b * NN + qi) * 3;
        float qvf = (qp[2] == 1.0f) ? 1.0f : 0.0f;
        a5 += sqrtf(fmaxf(m, 1e-12f)) * qvf;
        a6 += qvf;
    }

    float v[7] = {a0, a1, a2, a3, a4, a5, a6};
    const int wave = tid >> 6, lane = tid & 63;
#pragma unroll
    for (int i = 0; i < 7; i++) {
        float rv = wred(v[i]);
        if (lane == 0) sred[i][wave] = rv;
    }
    __syncthreads();

    if (tid == 0) {
        float s[7];
#pragma unroll
        for (int i = 0; i < 7; i++) {
            float acc = 0.0f;
#pragma unroll
            for (int w = 0; w < TB2 / 64; w++) acc += sred[i][w];
            s[i] = acc;
        }
        float sp = s[0], cp = s[1], spt = s[2], sst = s[3];
        float st_ = s[5], ct = s[6];
        float mp = sp / fmaxf(cp, 1.0f);
        float mt = st_ / fmaxf(ct, 1.0f);
        float ch = (cp > 0.0f && ct > 0.0f) ? 0.5f * (mp + mt) : 0.0f;

        const float denom = (float)BB * (float)NN * 2.0f;
        float lp = spt / denom;
        float ls = sst / denom;
        float lc = ch / (float)BB;

        atomicAdd(&out[0], lp + 5.0f * lc + 2.0f * ls);
        atomicAdd(&out[1], lp);
        atomicAdd(&out[3], lc);
        // out[2] stays 0 (zeroed by k1)
    }
}

extern "C" void kernel_launch(void* const* d_in, const int* in_sizes, int n_in,
                              void* d_out, int out_size, void* d_ws, size_t ws_size,
                              hipStream_t stream)
{
    const float* pred  = (const float*)d_in[0];
    const float* tgt   = (const float*)d_in[1];
    const float* smask = (const float*)d_in[2];
    float* out = (float*)d_out;
    float* part = (float*)d_ws;   // 8.4 MB

    k1_chamfer<<<dim3(1, BB, RCH), TB, 0, stream>>>(pred, tgt, part, out);
    k2_final<<<dim3(BB), TB2, 0, stream>>>(pred, tgt, smask, part, out);
}

// Round 10
// 80.612 us; speedup vs baseline: 1.0751x; 1.0091x over previous
//
#include <hip/hip_runtime.h>
#include <math.h>

#define BB 32
#define NN 2048
#define TB 256            // k1 threads
#define QT 8              // queries per thread in k1 -> 2048 = NN per block
#define RCH 16            // ref chunks (split of the min over refs)
#define MCH (NN / RCH)    // 128 refs per chunk
#define TB2 512           // k2 threads

typedef float v2f __attribute__((ext_vector_type(2)));

// ws layout: part[RCH][2*BB][NN] floats (8.4 MB, no init needed)

__device__ __forceinline__ float wred(float v) {
#pragma unroll
    for (int o = 32; o > 0; o >>= 1) v += __shfl_down(v, o, 64);
    return v;
}

__device__ __forceinline__ float min3(float a, float b, float c) {
    return fminf(fminf(a, b), c);   // -> v_min3_f32
}

// K1 — round-6 structure (best: 80.3us) with packed-f32 inner math.
// grid (1, BB, 2*RCH); blockIdx.z = rc*2 + role; 1024 blocks = 4/CU.
// Query broadcast pairs {px,px},{py,py} are HOISTED out of the m-loop
// (R7 rebuilt them per-iter — the movs ate the pk_fma gain). Refs come out
// of ds_read_b128 as aligned register pairs, consumed directly by
// v_pk_fma_f32: per 8 refs per query = 8 pk_fma + 4 v_min3 = 1.5 VALU/pair
// (scalarized worst case == R6's 2.5 -> neutral). Block (0,0) zeroes out[];
// k1->k2 dispatch boundary is the cross-XCD release fence (R5 lesson).
__global__ __launch_bounds__(256) void k1_chamfer(
    const float* __restrict__ pred, const float* __restrict__ tgt,
    float* __restrict__ part, float* __restrict__ out)
{
    __shared__ float sa[MCH], sb[MCH], sc[MCH];

    const int tid  = threadIdx.x;
    const int b    = blockIdx.y;
    const int role = blockIdx.z & 1;
    const int rc   = blockIdx.z >> 1;

    if (b == 0 && blockIdx.z == 0 && tid < 4) out[tid] = 0.0f;

    const float* q = role ? tgt : pred;
    const float* r = role ? pred : tgt;
    const float* rb = r + ((size_t)b * NN + (size_t)rc * MCH) * 3;

    if (tid < MCH) {
        float rx = rb[3 * tid + 0];
        float ry = rb[3 * tid + 1];
        float rv = rb[3 * tid + 2];
        if (rv != 1.0f) { rx = 1.0e9f; ry = 1.0e9f; }   // d2 ~ 2e18, never wins
        sa[tid] = -2.0f * rx;
        sb[tid] = -2.0f * ry;
        sc[tid] = fmaf(rx, rx, ry * ry);
    }
    __syncthreads();

    const float* qb_ = q + (size_t)b * NN * 3;
    float px[QT], py[QT], mn[QT];
    v2f px2[QT], py2[QT];                 // loop-invariant broadcast pairs
#pragma unroll
    for (int j = 0; j < QT; j++) {
        int qi = tid + j * TB;
        px[j] = qb_[3 * qi + 0];
        py[j] = qb_[3 * qi + 1];
        px2[j] = (v2f){px[j], px[j]};
        py2[j] = (v2f){py[j], py[j]};
        mn[j] = 3.4e38f;
    }

    // 8 refs/iter: 6 uniform ds_read_b128 (broadcast, conflict-free); the
    // float4 halves are even-aligned VGPR pairs -> direct v_pk_fma_f32 srcs.
#pragma unroll 2
    for (int m = 0; m < MCH; m += 8) {
        float4 a04 = *(const float4*)&sa[m], a14 = *(const float4*)&sa[m + 4];
        float4 b04 = *(const float4*)&sb[m], b14 = *(const float4*)&sb[m + 4];
        float4 c04 = *(const float4*)&sc[m], c14 = *(const float4*)&sc[m + 4];
        v2f a01 = {a04.x, a04.y}, a23 = {a04.z, a04.w};
        v2f a45 = {a14.x, a14.y}, a67 = {a14.z, a14.w};
        v2f b01 = {b04.x, b04.y}, b23 = {b04.z, b04.w};
        v2f b45 = {b14.x, b14.y}, b67 = {b14.z, b14.w};
        v2f c01 = {c04.x, c04.y}, c23 = {c04.z, c04.w};
        v2f c45 = {c14.x, c14.y}, c67 = {c14.z, c14.w};
#pragma unroll
        for (int j = 0; j < QT; j++) {
            v2f s01 = __builtin_elementwise_fma(px2[j], a01,
                        __builtin_elementwise_fma(py2[j], b01, c01));
            v2f s23 = __builtin_elementwise_fma(px2[j], a23,
                        __builtin_elementwise_fma(py2[j], b23, c23));
            v2f s45 = __builtin_elementwise_fma(px2[j], a45,
                        __builtin_elementwise_fma(py2[j], b45, c45));
            v2f s67 = __builtin_elementwise_fma(px2[j], a67,
                        __builtin_elementwise_fma(py2[j], b67, c67));
            float u = min3(s01.x, s01.y, s23.x);
            float v = min3(s23.y, s45.x, s45.y);
            float w = min3(s67.x, s67.y, mn[j]);
            mn[j] = min3(u, v, w);
        }
    }

#pragma unroll
    for (int j = 0; j < QT; j++) {
        int qi = tid + j * TB;
        float qn = fmaf(px[j], px[j], py[j] * py[j]);
        part[((size_t)rc * (2 * BB) + role * BB + b) * NN + qi] = qn + mn[j];
    }
}

// K2 — exact round-6 version (proven best): grid (BB) = 32 blocks, 512 thr.
// Block b owns batch b, BOTH roles: 16-plane min per query, sqrt+mask
// epilogue, block-reduce 7 sums, chamfer_b local, atomicAdd linear terms.
// smk>0 gate is redundant: smk==0 => every struct term is 0 => sum is 0.
__global__ __launch_bounds__(TB2) void k2_final(
    const float* __restrict__ pred, const float* __restrict__ tgt,
    const float* __restrict__ smask, const float* __restrict__ part,
    float* __restrict__ out)
{
    __shared__ float sred[7][8];
    const int tid = threadIdx.x;
    const int b   = blockIdx.x;

    float a0 = 0, a1 = 0, a2 = 0, a3 = 0, a4 = 0, a5 = 0, a6 = 0;

    // role 0 (queries = pred): contrib_p, cnt_p, point/struct/mask sums
#pragma unroll
    for (int j = 0; j < NN / TB2; j++) {
        int qi = tid + j * TB2;
        float m = 3.4e38f;
#pragma unroll
        for (int k = 0; k < RCH; k++)
            m = fminf(m, part[((size_t)k * (2 * BB) + b) * NN + qi]);

        const float* qp = pred + ((size_t)b * NN + qi) * 3;
        float qvf = (qp[2] == 1.0f) ? 1.0f : 0.0f;
        a0 += sqrtf(fmaxf(m, 1e-12f)) * qvf;
        a1 += qvf;

        const float* tp = tgt + ((size_t)b * NN + qi) * 3;
        float vm = (tp[2] == 1.0f) ? 1.0f : 0.0f;
        float dx = qp[0] - tp[0], dy = qp[1] - tp[1];
        float e2 = fmaf(dx, dx, dy * dy);
        float s0 = smask[((size_t)b * NN + qi) * 2 + 0];
        float s1 = smask[((size_t)b * NN + qi) * 2 + 1];
        float tm = fminf(fmaxf(s0 + s1, 0.0f), 1.0f) * vm;
        a2 += e2 * vm;
        a3 += e2 * tm;
        a4 += tm;
    }

    // role 1 (queries = tgt): contrib_t, cnt_t
#pragma unroll
    for (int j = 0; j < NN / TB2; j++) {
        int qi = tid + j * TB2;
        float m = 3.4e38f;
#pragma unroll
        for (int k = 0; k < RCH; k++)
            m = fminf(m, part[((size_t)k * (2 * BB) + BB + b) * NN + qi]);

        const float* qp = tgt + ((size_t)b * NN + qi) * 3;
        float qvf = (qp[2] == 1.0f) ? 1.0f : 0.0f;
        a5 += sqrtf(fmaxf(m, 1e-12f)) * qvf;
        a6 += qvf;
    }

    float v[7] = {a0, a1, a2, a3, a4, a5, a6};
    const int wave = tid >> 6, lane = tid & 63;
#pragma unroll
    for (int i = 0; i < 7; i++) {
        float rv = wred(v[i]);
        if (lane == 0) sred[i][wave] = rv;
    }
    __syncthreads();

    if (tid == 0) {
        float s[7];
#pragma unroll
        for (int i = 0; i < 7; i++) {
            float acc = 0.0f;
#pragma unroll
            for (int w = 0; w < TB2 / 64; w++) acc += sred[i][w];
            s[i] = acc;
        }
        float sp = s[0], cp = s[1], spt = s[2], sst = s[3];
        float st_ = s[5], ct = s[6];
        float mp = sp / fmaxf(cp, 1.0f);
        float mt = st_ / fmaxf(ct, 1.0f);
        float ch = (cp > 0.0f && ct > 0.0f) ? 0.5f * (mp + mt) : 0.0f;

        const float denom = (float)BB * (float)NN * 2.0f;
        float lp = spt / denom;
        float ls = sst / denom;
        float lc = ch / (float)BB;

        atomicAdd(&out[0], lp + 5.0f * lc + 2.0f * ls);
        atomicAdd(&out[1], lp);
        atomicAdd(&out[3], lc);
        // out[2] stays 0 (zeroed by k1)
    }
}

extern "C" void kernel_launch(void* const* d_in, const int* in_sizes, int n_in,
                              void* d_out, int out_size, void* d_ws, size_t ws_size,
                              hipStream_t stream)
{
    const float* pred  = (const float*)d_in[0];
    const float* tgt   = (const float*)d_in[1];
    const float* smask = (const float*)d_in[2];
    float* out = (float*)d_out;
    float* part = (float*)d_ws;   // 8.4 MB

    k1_chamfer<<<dim3(1, BB, 2 * RCH), TB, 0, stream>>>(pred, tgt, part, out);
    k2_final<<<dim3(BB), TB2, 0, stream>>>(pred, tgt, smask, part, out);
}